// Round 6
// baseline (605.668 us; speedup 1.0000x reference)
//
#include <hip/hip_runtime.h>
#include <cstdint>

// B=32, T=2048, D=1024.  scores[b,t] = v · relu(W_h·hidden[b] + W_e·enc[b,t] + bias)
// out = softmax_T(scores).
// R9: revert GEMM to the harness-verified R3 2-barrier 128x128x64 structure
// (170 µs, 3-4 blocks/CU TLP) and host the enc fp32->bf16 conversion INSIDE it:
// A is reg-staged (8 float4/thread), cvt+ds_write at loop top, k+1 prefetch issued
// after the first barrier so it overlaps the 32-MFMA compute and retires at the
// natural __syncthreads drain. No manual waitcnt. B path, XOR swizzle, fragment
// reads verbatim R3 (0 bank conflicts verified). Grid 4096 = 512 mb x 8 nb,
// XCD-swizzled (all 8 nb of an mb on one XCD -> A L2/L3-shared). 8-phase
// experiment concluded: it never beat 2-barrier here (188/306 vs 170 µs).
// convert_we fused into hidden_proj; kernels 5 -> 3 (+softmax).

#define GLOBAL_AS __attribute__((address_space(1)))
#define LDS_AS    __attribute__((address_space(3)))

typedef __bf16 bf16x8 __attribute__((ext_vector_type(8)));
typedef float  f32x4  __attribute__((ext_vector_type(4)));

__device__ __forceinline__ unsigned int f2bf(float x) {
    unsigned int u = __builtin_bit_cast(unsigned int, x);
    u += 0x7fffu + ((u >> 16) & 1u);   // RNE
    return u >> 16;
}

// ---- u[b,d] = hidden[b,:]·W[d,0:1024] + bias[d]; also converts W_e row d ----
__global__ __launch_bounds__(256) void k_hidden_proj(const float* __restrict__ hidden,
                                                     const float* __restrict__ W,
                                                     const float* __restrict__ bias,
                                                     float* __restrict__ u,
                                                     uint2* __restrict__ Web) {
    __shared__ float wrow[1024];
    __shared__ float red[256];
    const int tid = threadIdx.x, d = blockIdx.x;
    // fused convert_we: W[d,1024+4t..+4) -> Web row d (bf16, k-contiguous)
    {
        const float4 wf = *(const float4*)(W + (size_t)d * 2048 + 1024 + tid * 4);
        uint2 o;
        o.x = f2bf(wf.x) | (f2bf(wf.y) << 16);
        o.y = f2bf(wf.z) | (f2bf(wf.w) << 16);
        Web[d * 256 + tid] = o;
    }
    ((float4*)wrow)[tid] = ((const float4*)(W + (size_t)d * 2048))[tid];
    __syncthreads();
    const int b = tid & 31, kc = tid >> 5;
    const float* h = hidden + b * 1024 + kc * 128;
    const float* w = wrow + kc * 128;
    float acc = 0.f;
    #pragma unroll 8
    for (int i = 0; i < 128; i += 4) {
        float4 hv = *(const float4*)(h + i);
        acc += w[i] * hv.x + w[i + 1] * hv.y + w[i + 2] * hv.z + w[i + 3] * hv.w;
    }
    red[tid] = acc;
    __syncthreads();
    if (tid < 32) {
        float s = 0.f;
        #pragma unroll
        for (int j = 0; j < 8; j++) s += red[j * 32 + tid];
        u[tid * 1024 + d] = s + bias[d];
    }
}

// ---- GEMM (fused enc convert) + relu·v score. grid 4096 = 512 mb x 8 nb ----
__global__ __launch_bounds__(256, 3) void k_gemm_score(
        const float* __restrict__ Af,            // enc fp32 [65536,1024]
        const unsigned short* __restrict__ Bw,   // W_e bf16 [1024,1024]
        const float* __restrict__ u,             // [32,1024] (incl. bias)
        const float* __restrict__ v,             // [1024]
        float* __restrict__ scores8) {           // [8,65536]
    constexpr int K = 1024, BK = 64;
    __shared__ __align__(16) unsigned short As[128 * BK];  // 16 KB
    __shared__ __align__(16) unsigned short Bs[128 * BK];  // 16 KB
    __shared__ float red[2][128];

    const int tid  = threadIdx.x;
    const int wave = tid >> 6;
    const int lane = tid & 63;
    // XCD swizzle: bid&7 = XCD; each XCD owns 512 consecutive logical tiles
    // = 64 mb-groups x 8 nb -> the 8 nb-blocks of an mb co-reside on one XCD.
    const int bid  = blockIdx.x;
    const int lg   = (bid & 7) * 512 + (bid >> 3);
    const int mb   = lg >> 3;          // 0..511
    const int nb   = lg & 7;           // 0..7
    const int wm = wave & 1, wn = wave >> 1;
    const int q = lane >> 4, cl = lane & 15;

    // fragment LDS offsets (shorts) for k-half h=0; h=1 is ^32 (granule^4).
    // row r, k-granule G in [0,8): offset = r*64 + ((G ^ (r&7))<<3)   [R3 verbatim]
    int aoff[4], boff[4];
    #pragma unroll
    for (int i = 0; i < 4; i++) {
        int ra = wm * 64 + i * 16 + cl;
        aoff[i] = ra * 64 + ((q ^ (ra & 7)) << 3);
        int rb = wn * 64 + i * 16 + cl;
        boff[i] = rb * 64 + ((q ^ (rb & 7)) << 3);
    }

    // B staging via global_load_lds: 16 chunks of 1KB; wave does chunks wave*4+c
    // lane -> row = chunk*8 + (lane>>3), slot = lane&7, granule = slot ^ (row&7)
    int soffB[4];
    #pragma unroll
    for (int c = 0; c < 4; c++) {
        int row = (wave * 4 + c) * 8 + (lane >> 3);
        int g   = (lane & 7) ^ (row & 7);
        soffB[c] = row * K + g * 8;
    }
    const unsigned short* Bbase = Bw + (size_t)(nb * 128) * K;

    // A reg-staging: thread covers row ar = tid>>1, cols [(tid&1)*32, +32) of the
    // BK window; 4 granules G = (tid&1)*4 + g written XOR-swizzled.
    const int ar  = tid >> 1;
    const int ac0 = (tid & 1) * 32;
    const float* Arow = Af + (size_t)(mb * 128 + ar) * K + ac0;
    int awoff[4];
    #pragma unroll
    for (int g = 0; g < 4; g++) {
        int G = (tid & 1) * 4 + g;
        awoff[g] = ar * 64 + ((G ^ (ar & 7)) << 3);
    }

    const int bidx = mb >> 4;                    // batch = (mb*128)/2048

    float4 aL[8];
    #pragma unroll
    for (int x = 0; x < 8; x++) aL[x] = *(const float4*)(Arow + x * 4);

    f32x4 acc[4][4];
    #pragma unroll
    for (int i = 0; i < 4; i++)
        #pragma unroll
        for (int j = 0; j < 4; j++) acc[i][j] = (f32x4){0.f, 0.f, 0.f, 0.f};

    for (int k0 = 0; k0 < K; k0 += BK) {
        // write A(k0) from regs (cvt to bf16, swizzled granules)
        #pragma unroll
        for (int g = 0; g < 4; g++) {
            float4 lo = aL[2 * g], hi = aL[2 * g + 1];
            bf16x8 w;
            w[0] = (__bf16)lo.x; w[1] = (__bf16)lo.y; w[2] = (__bf16)lo.z; w[3] = (__bf16)lo.w;
            w[4] = (__bf16)hi.x; w[5] = (__bf16)hi.y; w[6] = (__bf16)hi.z; w[7] = (__bf16)hi.w;
            *(bf16x8*)(As + awoff[g]) = w;
        }
        // stage B(k0)
        #pragma unroll
        for (int c = 0; c < 4; c++)
            __builtin_amdgcn_global_load_lds(
                (GLOBAL_AS void*)(size_t)(Bbase + soffB[c] + k0),
                (LDS_AS void*)(Bs + (wave * 4 + c) * 512), 16, 0, 0);
        __syncthreads();   // drains A ds_writes (lgkm) + B gloads (vmcnt)

        // prefetch A(k0+64) — overlaps the MFMA cluster, retires at next barrier
        if (k0 + BK < K) {
            #pragma unroll
            for (int x = 0; x < 8; x++)
                aL[x] = *(const float4*)(Arow + (k0 + BK) + x * 4);
        }

        #pragma unroll
        for (int h = 0; h < 2; h++) {
            const int hx = h * 32;   // granule^4 == short-offset^32
            bf16x8 afr[4], bfr[4];
            #pragma unroll
            for (int i = 0; i < 4; i++) afr[i] = *(const bf16x8*)(As + (aoff[i] ^ hx));
            #pragma unroll
            for (int j = 0; j < 4; j++) bfr[j] = *(const bf16x8*)(Bs + (boff[j] ^ hx));
            #pragma unroll
            for (int i = 0; i < 4; i++)
                #pragma unroll
                for (int j = 0; j < 4; j++)
                    acc[i][j] = __builtin_amdgcn_mfma_f32_16x16x32_bf16(afr[i], bfr[j], acc[i][j], 0, 0, 0);
        }
        __syncthreads();   // protect LDS overwrite next iter
    }

    // epilogue: fold relu(E+u)·v once, shfl-reduce 16 cl-lanes, LDS-reduce 2 wn
    float vv[4], uu[4];
    #pragma unroll
    for (int j = 0; j < 4; j++) {
        int n = nb * 128 + wn * 64 + j * 16 + cl;
        vv[j] = v[n];
        uu[j] = u[bidx * 1024 + n];
    }
    #pragma unroll
    for (int i = 0; i < 4; i++)
        #pragma unroll
        for (int r = 0; r < 4; r++) {
            float s = 0.f;
            #pragma unroll
            for (int j = 0; j < 4; j++)
                s += fmaxf(acc[i][j][r] + uu[j], 0.f) * vv[j];
            s += __shfl_xor(s, 1);
            s += __shfl_xor(s, 2);
            s += __shfl_xor(s, 4);
            s += __shfl_xor(s, 8);
            if (cl == 0) red[wn][wm * 64 + i * 16 + q * 4 + r] = s;
        }
    __syncthreads();
    if (tid < 128) scores8[(size_t)nb * 65536 + mb * 128 + tid] = red[0][tid] + red[1][tid];
}

// ---- softmax over T=2048 per batch; sums the eight nb-partials ----
__global__ __launch_bounds__(256) void k_softmax(const float* __restrict__ scores8,
                                                 float* __restrict__ out) {
    __shared__ float red[4];
    int b = blockIdx.x;
    int t0 = threadIdx.x;
    int wave = threadIdx.x >> 6, lane = threadIdx.x & 63;
    const float* s0 = scores8 + b * 2048;
    float vals[8];
    float lmax = -1e30f;
    #pragma unroll
    for (int i = 0; i < 8; i++) {
        int t = t0 + i * 256;
        float s = 0.f;
        #pragma unroll
        for (int qd = 0; qd < 8; qd++) s += s0[(size_t)qd * 65536 + t];
        vals[i] = s;
        lmax = fmaxf(lmax, vals[i]);
    }
    for (int o = 32; o > 0; o >>= 1) lmax = fmaxf(lmax, __shfl_xor(lmax, o));
    if (lane == 0) red[wave] = lmax;
    __syncthreads();
    float gmax = fmaxf(fmaxf(red[0], red[1]), fmaxf(red[2], red[3]));
    float lsum = 0.f;
    #pragma unroll
    for (int i = 0; i < 8; i++) {
        vals[i] = expf(vals[i] - gmax);
        lsum += vals[i];
    }
    for (int o = 32; o > 0; o >>= 1) lsum += __shfl_xor(lsum, o);
    __syncthreads();
    if (lane == 0) red[wave] = lsum;
    __syncthreads();
    float inv = 1.0f / (red[0] + red[1] + red[2] + red[3]);
    #pragma unroll
    for (int i = 0; i < 8; i++) out[b * 2048 + t0 + i * 256] = vals[i] * inv;
}

extern "C" void kernel_launch(void* const* d_in, const int* in_sizes, int n_in,
                              void* d_out, int out_size, void* d_ws, size_t ws_size,
                              hipStream_t stream) {
    const float* hidden = (const float*)d_in[0];  // [32,1024]
    const float* enc    = (const float*)d_in[1];  // [32,2048,1024]
    const float* W      = (const float*)d_in[2];  // [1024,2048]
    const float* bias   = (const float*)d_in[3];  // [1024]
    const float* v      = (const float*)d_in[4];  // [1024]
    float* out = (float*)d_out;                   // [32,1,2048]

    char* ws = (char*)d_ws;
    unsigned short* Web = (unsigned short*)ws;                        // 2 MB bf16 W_e
    float* u       = (float*)(ws + 2097152);                          // 128 KB
    float* scores8 = (float*)(ws + 2097152 + 131072);                 // 2 MB

    k_hidden_proj<<<1024, 256, 0, stream>>>(hidden, W, bias, u, (uint2*)Web);
    k_gemm_score<<<4096, 256, 0, stream>>>(enc, Web, u, v, scores8);
    k_softmax<<<32, 256, 0, stream>>>(scores8, out);
}